// Round 2
// baseline (178.997 us; speedup 1.0000x reference)
//
#include <hip/hip_runtime.h>
#include <cstdint>
#include <cstddef>

#define B_N 4096
#define V_N 6
#define D_N 256

typedef __bf16 bf16x8 __attribute__((ext_vector_type(8)));
typedef float f32x4 __attribute__((ext_vector_type(4)));

// round-to-nearest-even float -> bf16 bits (no NaN handling needed here)
__device__ __forceinline__ unsigned short f2bf(float f) {
  unsigned int u = __float_as_uint(f);
  unsigned int r = (u + 0x7fffu + ((u >> 16) & 1u)) >> 16;
  return (unsigned short)r;
}

// async global->LDS, 16B per lane. LDS dest is wave-uniform base + lane*16.
__device__ __forceinline__ void async_load16(void* lds, const void* gmem) {
  __builtin_amdgcn_global_load_lds(
      (const __attribute__((address_space(1))) unsigned int*)gmem,
      (__attribute__((address_space(3))) unsigned int*)lds,
      16, 0, 0);
}

// Kernel A: per-sample normalize (emit bf16 Zn, layout [v][b][d]) + pos term.
// acc[0] += sum_{v<w} exp(2*(1-sim_{b,v,w})) over all b
__global__ __launch_bounds__(256) void norm_pos_kernel(
    const float* __restrict__ z, unsigned short* __restrict__ znb,
    float* __restrict__ acc) {
  const int b = blockIdx.x;
  const int t = threadIdx.x;   // 256 threads
  const int lane = t & 63;
  const int w = t >> 6;        // wave 0..3

  __shared__ float zs[V_N][D_N];
  __shared__ float red[V_N][4];
  __shared__ float inv[V_N];
  __shared__ float pred[4];

  const float* zb = z + (size_t)b * (V_N * D_N);
#pragma unroll
  for (int v = 0; v < V_N; ++v) zs[v][t] = zb[v * D_N + t];
  __syncthreads();

#pragma unroll
  for (int v = 0; v < V_N; ++v) {
    float x = zs[v][t];
    float s = x * x;
#pragma unroll
    for (int off = 32; off > 0; off >>= 1) s += __shfl_down(s, off);
    if (lane == 0) red[v][w] = s;
  }
  __syncthreads();
  if (t < V_N) inv[t] = rsqrtf(red[t][0] + red[t][1] + red[t][2] + red[t][3]);
  __syncthreads();

#pragma unroll
  for (int v = 0; v < V_N; ++v) {
    float zn = zs[v][t] * inv[v];
    znb[((size_t)v * B_N + b) * D_N + t] = f2bf(zn);
  }

  // pos: 15 unique (v<w) pairs, round-robin over the 4 waves
  float psum = 0.0f;
  int pidx = 0;
#pragma unroll
  for (int v = 0; v < V_N; ++v) {
#pragma unroll
    for (int u = v + 1; u < V_N; ++u) {
      if ((pidx & 3) == w) {
        float s = 0.0f;
#pragma unroll
        for (int d = 0; d < D_N; d += 64) s += zs[v][lane + d] * zs[u][lane + d];
#pragma unroll
        for (int off = 32; off > 0; off >>= 1) s += __shfl_down(s, off);
        if (lane == 0) {
          float sim = s * inv[v] * inv[u];
          psum += __expf(2.0f * (1.0f - sim));
        }
      }
      ++pidx;
    }
  }
  if (lane == 0) pred[w] = psum;
  __syncthreads();
  if (t == 0) atomicAdd(&acc[0], pred[0] + pred[1] + pred[2] + pred[3]);
}

// Kernel B: per view, lower-triangle 128x128 tiles of Zn_v * Zn_v^T (K=256),
// fused exp(2*sim) + full reduction. acc[1] += sum over ALL off-diagonal
// (b,c) entries of exp(2*sim) (off-diag tiles weighted x2 by symmetry).
__global__ __launch_bounds__(256) void gram_kernel(
    const unsigned short* __restrict__ znb, float* __restrict__ acc) {
  const int v = blockIdx.y;
  const int t = blockIdx.x;  // 0..527 triangle index
  int i = (int)((sqrtf(8.0f * (float)t + 1.0f) - 1.0f) * 0.5f);
  while ((i + 1) * (i + 2) / 2 <= t) ++i;
  while (i * (i + 1) / 2 > t) --i;
  const int j = t - i * (i + 1) / 2;  // i >= j

  const unsigned short* Zv = znb + (size_t)v * B_N * D_N;
  const unsigned short* Ag = Zv + (size_t)(i * 128) * D_N;
  const unsigned short* Bg = Zv + (size_t)(j * 128) * D_N;

  __shared__ __bf16 As[128][32];  // 8192 B: 512 x 16B segments -> 2 per thread
  __shared__ __bf16 Bs[128][32];
  __shared__ float blk[4];

  const int tid = threadIdx.x;  // 256
  const int lane = tid & 63;
  const int w = tid >> 6;
  const int wr = w >> 1;   // wave row 0..1 (64-row strip)
  const int wc = w & 1;    // wave col 0..1 (64-col strip)
  // staging: segment s (0..511) -> row s>>2, 16B chunk s&3. Thread covers
  // segments tid and tid+256 (fixes round-1 bug: only half the tile staged).
  const int lrow = tid >> 2;
  const int lseg = tid & 3;

  const f32x4 vzero = {0.0f, 0.0f, 0.0f, 0.0f};
  f32x4 c[4][4];
#pragma unroll
  for (int a = 0; a < 4; ++a)
#pragma unroll
    for (int b2 = 0; b2 < 4; ++b2) c[a][b2] = vzero;

  const int kq = (lane >> 4) * 8;         // A/B operand k-offset for this lane
  const int mrow = wr * 64 + (lane & 15); // A fragment base row
  const int ncol = wc * 64 + (lane & 15); // B fragment base row (= C column)

  __bf16* AsF = &As[0][0];
  __bf16* BsF = &Bs[0][0];

  for (int k0 = 0; k0 < D_N; k0 += 32) {
    __syncthreads();  // previous iteration's LDS reads done
    // lower half (rows 0..63): segments tid
    async_load16(AsF + tid * 8, Ag + (size_t)lrow * D_N + k0 + lseg * 8);
    async_load16(BsF + tid * 8, Bg + (size_t)lrow * D_N + k0 + lseg * 8);
    // upper half (rows 64..127): segments tid+256
    async_load16(AsF + (tid + 256) * 8,
                 Ag + (size_t)(lrow + 64) * D_N + k0 + lseg * 8);
    async_load16(BsF + (tid + 256) * 8,
                 Bg + (size_t)(lrow + 64) * D_N + k0 + lseg * 8);
    __syncthreads();  // compiler emits vmcnt(0) drain before barrier

    bf16x8 af[4], bfr[4];
#pragma unroll
    for (int f = 0; f < 4; ++f) {
      af[f]  = *(const bf16x8*)&As[mrow + 16 * f][kq];
      bfr[f] = *(const bf16x8*)&Bs[ncol + 16 * f][kq];
    }
#pragma unroll
    for (int fm = 0; fm < 4; ++fm)
#pragma unroll
      for (int fn = 0; fn < 4; ++fn)
        c[fm][fn] = __builtin_amdgcn_mfma_f32_16x16x32_bf16(
            af[fm], bfr[fn], c[fm][fn], 0, 0, 0);
  }

  // epilogue: exp(2*sim), drop b==c diagonal, reduce
  float lsum = 0.0f;
  const int rb = i * 128 + wr * 64 + (lane >> 4) * 4;  // C/D: row=(lane>>4)*4+reg
  const int cb = j * 128 + wc * 64 + (lane & 15);      // C/D: col=lane&15
#pragma unroll
  for (int fm = 0; fm < 4; ++fm) {
#pragma unroll
    for (int fn = 0; fn < 4; ++fn) {
      const int gcol = cb + fn * 16;
#pragma unroll
      for (int r = 0; r < 4; ++r) {
        const int grow = rb + fm * 16 + r;
        float e = __expf(2.0f * c[fm][fn][r]);
        lsum += (grow == gcol) ? 0.0f : e;
      }
    }
  }
  if (i != j) lsum *= 2.0f;  // symmetric twin tile

#pragma unroll
  for (int off = 32; off > 0; off >>= 1) lsum += __shfl_down(lsum, off);
  if (lane == 0) blk[w] = lsum;
  __syncthreads();
  if (tid == 0) atomicAdd(&acc[1], blk[0] + blk[1] + blk[2] + blk[3]);
}

__global__ void finalize_kernel(const float* __restrict__ acc,
                                float* __restrict__ out) {
  const float P = acc[0];  // sum_b sum_{v<w} exp(2(1-sim))
  const float N = acc[1];  // sum_v sum_{b!=c} exp(2 sim)
  // sum(pos) = (6*B + 2P)/36 = B/6 + P/18 ; sum(neg) = N/(B-1)
  out[0] = (1.0f / 32.0f) * ((float)B_N / 6.0f + P / 18.0f) +
           0.0039f * (N / (float)(B_N - 1));
}

extern "C" void kernel_launch(void* const* d_in, const int* in_sizes, int n_in,
                              void* d_out, int out_size, void* d_ws, size_t ws_size,
                              hipStream_t stream) {
  const float* z = (const float*)d_in[0];
  float* out = (float*)d_out;
  float* acc = (float*)d_ws;                                   // acc[0]=P, acc[1]=N
  unsigned short* znb = (unsigned short*)((char*)d_ws + 256);  // bf16 Zn [V][B][D]

  hipMemsetAsync(d_ws, 0, 256, stream);
  norm_pos_kernel<<<B_N, 256, 0, stream>>>(z, znb, acc);
  dim3 grid(528, V_N, 1);  // 32*33/2 triangle tiles x 6 views
  gram_kernel<<<grid, 256, 0, stream>>>(znb, acc);
  finalize_kernel<<<1, 1, 0, stream>>>(acc, out);
}

// Round 3
// 123.208 us; speedup vs baseline: 1.4528x; 1.4528x over previous
//
#include <hip/hip_runtime.h>
#include <cstdint>
#include <cstddef>

#define B_N 4096
#define V_N 6
#define D_N 256
#define NTILE 528  // 32*33/2 triangle tiles per view

typedef __bf16 bf16x8 __attribute__((ext_vector_type(8)));
typedef float f32x4 __attribute__((ext_vector_type(4)));

// round-to-nearest-even float -> bf16 bits
__device__ __forceinline__ unsigned short f2bf(float f) {
  unsigned int u = __float_as_uint(f);
  unsigned int r = (u + 0x7fffu + ((u >> 16) & 1u)) >> 16;
  return (unsigned short)r;
}

// async global->LDS, 16B per lane. LDS dest is wave-uniform base + lane*16.
__device__ __forceinline__ void async_load16(void* lds, const void* gmem) {
  __builtin_amdgcn_global_load_lds(
      (const __attribute__((address_space(1))) unsigned int*)gmem,
      (__attribute__((address_space(3))) unsigned int*)lds,
      16, 0, 0);
}

// Kernel A: per-sample normalize (emit bf16 Zn, layout [v][b][d]) + pos term.
// pos_part[b] = sum_{v<w} exp(2*(1-sim_{b,v,w}))   (no atomics: 1 slot/block)
__global__ __launch_bounds__(256) void norm_pos_kernel(
    const float* __restrict__ z, unsigned short* __restrict__ znb,
    float* __restrict__ pos_part) {
  const int b = blockIdx.x;
  const int t = threadIdx.x;   // 256 threads
  const int lane = t & 63;
  const int w = t >> 6;        // wave 0..3

  __shared__ float zs[V_N][D_N];
  __shared__ float red[V_N][4];
  __shared__ float inv[V_N];
  __shared__ float pred[4];

  const float* zb = z + (size_t)b * (V_N * D_N);
#pragma unroll
  for (int v = 0; v < V_N; ++v) zs[v][t] = zb[v * D_N + t];
  __syncthreads();

#pragma unroll
  for (int v = 0; v < V_N; ++v) {
    float x = zs[v][t];
    float s = x * x;
#pragma unroll
    for (int off = 32; off > 0; off >>= 1) s += __shfl_down(s, off);
    if (lane == 0) red[v][w] = s;
  }
  __syncthreads();
  if (t < V_N) inv[t] = rsqrtf(red[t][0] + red[t][1] + red[t][2] + red[t][3]);
  __syncthreads();

#pragma unroll
  for (int v = 0; v < V_N; ++v) {
    float zn = zs[v][t] * inv[v];
    znb[((size_t)v * B_N + b) * D_N + t] = f2bf(zn);
  }

  // pos: 15 unique (v<w) pairs, round-robin over the 4 waves
  float psum = 0.0f;
  int pidx = 0;
#pragma unroll
  for (int v = 0; v < V_N; ++v) {
#pragma unroll
    for (int u = v + 1; u < V_N; ++u) {
      if ((pidx & 3) == w) {
        float s = 0.0f;
#pragma unroll
        for (int d = 0; d < D_N; d += 64) s += zs[v][lane + d] * zs[u][lane + d];
#pragma unroll
        for (int off = 32; off > 0; off >>= 1) s += __shfl_down(s, off);
        if (lane == 0) {
          float sim = s * inv[v] * inv[u];
          psum += __expf(2.0f * (1.0f - sim));
        }
      }
      ++pidx;
    }
  }
  if (lane == 0) pred[w] = psum;
  __syncthreads();
  if (t == 0) pos_part[b] = pred[0] + pred[1] + pred[2] + pred[3];
}

// Kernel B: per view, lower-triangle 128x128 tiles of Zn_v * Zn_v^T (K=256),
// fused exp(2*sim) + block reduction -> neg_part[tile + 528*v].
// LDS layout XOR-swizzled: chunk' = chunk ^ ((row>>1)&3) to kill the 64B-row
// 4-way bank-quad conflicts (3.24M conflict cycles in round 2).
__global__ __launch_bounds__(256) void gram_kernel(
    const unsigned short* __restrict__ znb, float* __restrict__ neg_part) {
  const int v = blockIdx.y;
  const int t = blockIdx.x;  // 0..527 triangle index
  int i = (int)((sqrtf(8.0f * (float)t + 1.0f) - 1.0f) * 0.5f);
  while ((i + 1) * (i + 2) / 2 <= t) ++i;
  while (i * (i + 1) / 2 > t) --i;
  const int j = t - i * (i + 1) / 2;  // i >= j

  const unsigned short* Zv = znb + (size_t)v * B_N * D_N;
  const unsigned short* Ag = Zv + (size_t)(i * 128) * D_N;
  const unsigned short* Bg = Zv + (size_t)(j * 128) * D_N;

  __shared__ __bf16 As[128][32];  // 8192 B = 512 x 16B segments, swizzled
  __shared__ __bf16 Bs[128][32];
  __shared__ float blk[4];

  const int tid = threadIdx.x;  // 256
  const int lane = tid & 63;
  const int w = tid >> 6;
  const int wr = w >> 1;   // wave row 0..1 (64-row strip)
  const int wc = w & 1;    // wave col 0..1 (64-col strip)

  // staging source chunks for this thread's two segments (s and s+256):
  // LDS segment s -> row s>>2, swizzled chunk position s&3 holds
  // gmem chunk (s&3) ^ ((row>>1)&3)
  const int r0 = tid >> 2;
  const int c0 = (tid & 3) ^ ((r0 >> 1) & 3);
  const int r1 = r0 + 64;
  const int c1 = (tid & 3) ^ ((r1 >> 1) & 3);

  const f32x4 vzero = {0.0f, 0.0f, 0.0f, 0.0f};
  f32x4 c[4][4];
#pragma unroll
  for (int a = 0; a < 4; ++a)
#pragma unroll
    for (int b2 = 0; b2 < 4; ++b2) c[a][b2] = vzero;

  const int kc = lane >> 4;               // A/B operand k-chunk (16B) index
  const int mrow = wr * 64 + (lane & 15); // A fragment base row
  const int ncol = wc * 64 + (lane & 15); // B fragment base row (= C column)

  __bf16* AsF = &As[0][0];
  __bf16* BsF = &Bs[0][0];

  for (int k0 = 0; k0 < D_N; k0 += 32) {
    __syncthreads();  // previous iteration's LDS reads done
    async_load16(AsF + tid * 8,         Ag + (size_t)r0 * D_N + k0 + c0 * 8);
    async_load16(BsF + tid * 8,         Bg + (size_t)r0 * D_N + k0 + c0 * 8);
    async_load16(AsF + (tid + 256) * 8, Ag + (size_t)r1 * D_N + k0 + c1 * 8);
    async_load16(BsF + (tid + 256) * 8, Bg + (size_t)r1 * D_N + k0 + c1 * 8);
    __syncthreads();  // vmcnt(0) drain before barrier

    bf16x8 af[4], bfr[4];
#pragma unroll
    for (int f = 0; f < 4; ++f) {
      const int ra = mrow + 16 * f;
      const int rb2 = ncol + 16 * f;
      af[f]  = *(const bf16x8*)(AsF + ra * 32 + ((kc ^ ((ra >> 1) & 3)) * 8));
      bfr[f] = *(const bf16x8*)(BsF + rb2 * 32 + ((kc ^ ((rb2 >> 1) & 3)) * 8));
    }
#pragma unroll
    for (int fm = 0; fm < 4; ++fm)
#pragma unroll
      for (int fn = 0; fn < 4; ++fn)
        c[fm][fn] = __builtin_amdgcn_mfma_f32_16x16x32_bf16(
            af[fm], bfr[fn], c[fm][fn], 0, 0, 0);
  }

  // epilogue: exp(2*sim), drop b==c diagonal, reduce
  float lsum = 0.0f;
  const int rb = i * 128 + wr * 64 + (lane >> 4) * 4;  // C/D: row=(lane>>4)*4+reg
  const int cb = j * 128 + wc * 64 + (lane & 15);      // C/D: col=lane&15
#pragma unroll
  for (int fm = 0; fm < 4; ++fm) {
#pragma unroll
    for (int fn = 0; fn < 4; ++fn) {
      const int gcol = cb + fn * 16;
#pragma unroll
      for (int r = 0; r < 4; ++r) {
        const int grow = rb + fm * 16 + r;
        float e = __expf(2.0f * c[fm][fn][r]);
        lsum += (grow == gcol) ? 0.0f : e;
      }
    }
  }
  if (i != j) lsum *= 2.0f;  // symmetric twin tile

#pragma unroll
  for (int off = 32; off > 0; off >>= 1) lsum += __shfl_down(lsum, off);
  if (lane == 0) blk[w] = lsum;
  __syncthreads();
  if (tid == 0) neg_part[t + NTILE * v] = blk[0] + blk[1] + blk[2] + blk[3];
}

// Reduce the 4096 pos partials + 3168 neg partials, combine analytically.
__global__ __launch_bounds__(256) void finalize_kernel(
    const float* __restrict__ pos_part, const float* __restrict__ neg_part,
    float* __restrict__ out) {
  const int t = threadIdx.x;
  const int lane = t & 63;
  const int w = t >> 6;
  __shared__ float pr[4], nr[4];

  float p = 0.0f;
  for (int idx = t; idx < B_N; idx += 256) p += pos_part[idx];
  float n = 0.0f;
  for (int idx = t; idx < NTILE * V_N; idx += 256) n += neg_part[idx];
#pragma unroll
  for (int off = 32; off > 0; off >>= 1) {
    p += __shfl_down(p, off);
    n += __shfl_down(n, off);
  }
  if (lane == 0) { pr[w] = p; nr[w] = n; }
  __syncthreads();
  if (t == 0) {
    const float P = pr[0] + pr[1] + pr[2] + pr[3];
    const float N = nr[0] + nr[1] + nr[2] + nr[3];
    // sum(pos) = (6*B + 2P)/36 = B/6 + P/18 ; sum(neg) = N/(B-1)
    out[0] = (1.0f / 32.0f) * ((float)B_N / 6.0f + P / 18.0f) +
             0.0039f * (N / (float)(B_N - 1));
  }
}

extern "C" void kernel_launch(void* const* d_in, const int* in_sizes, int n_in,
                              void* d_out, int out_size, void* d_ws, size_t ws_size,
                              hipStream_t stream) {
  const float* z = (const float*)d_in[0];
  float* out = (float*)d_out;
  // ws layout: [0,4096) pos partials | [4096, 4096+3168) neg partials |
  //            32KB-aligned: bf16 Zn [V][B][D]
  float* pos_part = (float*)d_ws;
  float* neg_part = pos_part + B_N;
  unsigned short* znb = (unsigned short*)((char*)d_ws + 32768);

  norm_pos_kernel<<<B_N, 256, 0, stream>>>(z, znb, pos_part);
  dim3 grid(NTILE, V_N, 1);
  gram_kernel<<<grid, 256, 0, stream>>>(znb, neg_part);
  finalize_kernel<<<1, 256, 0, stream>>>(pos_part, neg_part, out);
}

// Round 4
// 116.226 us; speedup vs baseline: 1.5401x; 1.0601x over previous
//
#include <hip/hip_runtime.h>
#include <cstdint>
#include <cstddef>

#define B_N 4096
#define V_N 6
#define D_N 256
#define NTILE 528  // 32*33/2 triangle tiles per view

typedef __bf16 bf16x8 __attribute__((ext_vector_type(8)));
typedef float f32x4 __attribute__((ext_vector_type(4)));

// sqrt(2): folded into Zn so gram dot = 2*sim and epilogue is a bare __expf
#define ALPHA 1.41421356237309515f

// round-to-nearest-even float -> bf16 bits
__device__ __forceinline__ unsigned short f2bf(float f) {
  unsigned int u = __float_as_uint(f);
  unsigned int r = (u + 0x7fffu + ((u >> 16) & 1u)) >> 16;
  return (unsigned short)r;
}

// async global->LDS, 16B per lane. LDS dest is wave-uniform base + lane*16.
__device__ __forceinline__ void async_load16(void* lds, const void* gmem) {
  __builtin_amdgcn_global_load_lds(
      (const __attribute__((address_space(1))) unsigned int*)gmem,
      (__attribute__((address_space(3))) unsigned int*)lds,
      16, 0, 0);
}

// Kernel A: per-sample normalize (emit bf16 sqrt(2)*Zn, layout [v][b][d]) +
// pos term. pos_part[b] = sum_{v<w} exp(2*(1-sim_{b,v,w}))
__global__ __launch_bounds__(256) void norm_pos_kernel(
    const float* __restrict__ z, unsigned short* __restrict__ znb,
    float* __restrict__ pos_part) {
  const int b = blockIdx.x;
  const int t = threadIdx.x;   // 256 threads
  const int lane = t & 63;
  const int w = t >> 6;        // wave 0..3

  __shared__ float zs[V_N][D_N];
  __shared__ float red[V_N][4];
  __shared__ float inv[V_N];
  __shared__ float pred[4];

  const float* zb = z + (size_t)b * (V_N * D_N);
#pragma unroll
  for (int v = 0; v < V_N; ++v) zs[v][t] = zb[v * D_N + t];
  __syncthreads();

#pragma unroll
  for (int v = 0; v < V_N; ++v) {
    float x = zs[v][t];
    float s = x * x;
#pragma unroll
    for (int off = 32; off > 0; off >>= 1) s += __shfl_down(s, off);
    if (lane == 0) red[v][w] = s;
  }
  __syncthreads();
  if (t < V_N) inv[t] = rsqrtf(red[t][0] + red[t][1] + red[t][2] + red[t][3]);
  __syncthreads();

#pragma unroll
  for (int v = 0; v < V_N; ++v) {
    float zn = zs[v][t] * inv[v] * ALPHA;  // scaled: dot -> 2*sim directly
    znb[((size_t)v * B_N + b) * D_N + t] = f2bf(zn);
  }

  // pos: 15 unique (v<w) pairs, round-robin over the 4 waves
  float psum = 0.0f;
  int pidx = 0;
#pragma unroll
  for (int v = 0; v < V_N; ++v) {
#pragma unroll
    for (int u = v + 1; u < V_N; ++u) {
      if ((pidx & 3) == w) {
        float s = 0.0f;
#pragma unroll
        for (int d = 0; d < D_N; d += 64) s += zs[v][lane + d] * zs[u][lane + d];
#pragma unroll
        for (int off = 32; off > 0; off >>= 1) s += __shfl_down(s, off);
        if (lane == 0) {
          float sim = s * inv[v] * inv[u];
          psum += __expf(2.0f * (1.0f - sim));
        }
      }
      ++pidx;
    }
  }
  if (lane == 0) pred[w] = psum;
  __syncthreads();
  if (t == 0) pos_part[b] = pred[0] + pred[1] + pred[2] + pred[3];
}

// Kernel B: per view, lower-triangle 128x128 tiles of (a*Zn_v)(a*Zn_v)^T
// (K=256, BK=64, a=sqrt2 so acc = 2*sim), fused exp + block reduction ->
// neg_part[tile + 528*v]. LDS rows are 128B (8 x 16B chunks), XOR-swizzled
// chunk' = chunk ^ (row&7) for conflict-free ds_read_b128.
__global__ __launch_bounds__(256) void gram_kernel(
    const unsigned short* __restrict__ znb, float* __restrict__ neg_part) {
  const int v = blockIdx.y;
  const int t = blockIdx.x;  // 0..527 triangle index
  int i = (int)((sqrtf(8.0f * (float)t + 1.0f) - 1.0f) * 0.5f);
  while ((i + 1) * (i + 2) / 2 <= t) ++i;
  while (i * (i + 1) / 2 > t) --i;
  const int j = t - i * (i + 1) / 2;  // i >= j

  const unsigned short* Zv = znb + (size_t)v * B_N * D_N;
  const unsigned short* Ag = Zv + (size_t)(i * 128) * D_N;
  const unsigned short* Bg = Zv + (size_t)(j * 128) * D_N;

  __shared__ __bf16 As[128][64];  // 16 KB = 1024 x 16B segments
  __shared__ __bf16 Bs[128][64];
  __shared__ float blk[4];

  const int tid = threadIdx.x;  // 256
  const int lane = tid & 63;
  const int w = tid >> 6;
  const int wr = w >> 1;   // wave row 0..1 (64-row strip)
  const int wc = w & 1;    // wave col 0..1 (64-col strip)

  const f32x4 vzero = {0.0f, 0.0f, 0.0f, 0.0f};
  f32x4 c[4][4];
#pragma unroll
  for (int a = 0; a < 4; ++a)
#pragma unroll
    for (int b2 = 0; b2 < 4; ++b2) c[a][b2] = vzero;

  const int kc = lane >> 4;               // operand 16B-chunk index within 32-k
  const int mrow = wr * 64 + (lane & 15); // A fragment base row
  const int ncol = wc * 64 + (lane & 15); // B fragment base row (= C column)

  __bf16* AsF = &As[0][0];
  __bf16* BsF = &Bs[0][0];

  for (int k0 = 0; k0 < D_N; k0 += 64) {
    __syncthreads();  // previous iteration's LDS reads done
#pragma unroll
    for (int q = 0; q < 4; ++q) {
      const int s = tid + 256 * q;          // segment 0..1023
      const int row = s >> 3;               // 0..127
      const int gc = (s & 7) ^ (row & 7);   // gmem chunk feeding LDS pos s&7
      async_load16(AsF + s * 8, Ag + (size_t)row * D_N + k0 + gc * 8);
      async_load16(BsF + s * 8, Bg + (size_t)row * D_N + k0 + gc * 8);
    }
    __syncthreads();  // vmcnt(0) drain before barrier

#pragma unroll
    for (int kk = 0; kk < 2; ++kk) {
      const int cbase = kk * 4 + kc;
      bf16x8 af[4], bfr[4];
#pragma unroll
      for (int f = 0; f < 4; ++f) {
        const int ra = mrow + 16 * f;
        const int rb2 = ncol + 16 * f;
        af[f]  = *(const bf16x8*)(AsF + ra * 64 + ((cbase ^ (ra & 7)) * 8));
        bfr[f] = *(const bf16x8*)(BsF + rb2 * 64 + ((cbase ^ (rb2 & 7)) * 8));
      }
#pragma unroll
      for (int fm = 0; fm < 4; ++fm)
#pragma unroll
        for (int fn = 0; fn < 4; ++fn)
          c[fm][fn] = __builtin_amdgcn_mfma_f32_16x16x32_bf16(
              af[fm], bfr[fn], c[fm][fn], 0, 0, 0);
    }
  }

  // epilogue: acc already = 2*sim -> exp, drop b==c diagonal, reduce
  float lsum = 0.0f;
  const int rb = i * 128 + wr * 64 + (lane >> 4) * 4;  // C/D: row=(lane>>4)*4+reg
  const int cb = j * 128 + wc * 64 + (lane & 15);      // C/D: col=lane&15
#pragma unroll
  for (int fm = 0; fm < 4; ++fm) {
#pragma unroll
    for (int fn = 0; fn < 4; ++fn) {
      const int gcol = cb + fn * 16;
#pragma unroll
      for (int r = 0; r < 4; ++r) {
        const int grow = rb + fm * 16 + r;
        float e = __expf(c[fm][fn][r]);
        lsum += (grow == gcol) ? 0.0f : e;
      }
    }
  }
  if (i != j) lsum *= 2.0f;  // symmetric twin tile

#pragma unroll
  for (int off = 32; off > 0; off >>= 1) lsum += __shfl_down(lsum, off);
  if (lane == 0) blk[w] = lsum;
  __syncthreads();
  if (tid == 0) neg_part[t + NTILE * v] = blk[0] + blk[1] + blk[2] + blk[3];
}

// Reduce the 4096 pos partials + 3168 neg partials, combine analytically.
__global__ __launch_bounds__(1024) void finalize_kernel(
    const float* __restrict__ pos_part, const float* __restrict__ neg_part,
    float* __restrict__ out) {
  const int t = threadIdx.x;  // 1024
  const int lane = t & 63;
  const int w = t >> 6;       // 16 waves
  __shared__ float pr[16], nr[16];

  float p = 0.0f;
  for (int idx = t; idx < B_N; idx += 1024) p += pos_part[idx];
  float n = 0.0f;
  for (int idx = t; idx < NTILE * V_N; idx += 1024) n += neg_part[idx];
#pragma unroll
  for (int off = 32; off > 0; off >>= 1) {
    p += __shfl_down(p, off);
    n += __shfl_down(n, off);
  }
  if (lane == 0) { pr[w] = p; nr[w] = n; }
  __syncthreads();
  if (t == 0) {
    float P = 0.0f, N = 0.0f;
#pragma unroll
    for (int k = 0; k < 16; ++k) { P += pr[k]; N += nr[k]; }
    // sum(pos) = (6*B + 2P)/36 = B/6 + P/18 ; sum(neg) = N/(B-1)
    out[0] = (1.0f / 32.0f) * ((float)B_N / 6.0f + P / 18.0f) +
             0.0039f * (N / (float)(B_N - 1));
  }
}

extern "C" void kernel_launch(void* const* d_in, const int* in_sizes, int n_in,
                              void* d_out, int out_size, void* d_ws, size_t ws_size,
                              hipStream_t stream) {
  const float* z = (const float*)d_in[0];
  float* out = (float*)d_out;
  // ws layout: [0,4096) pos partials | [4096, 4096+3168) neg partials |
  //            32KB-aligned: bf16 sqrt(2)*Zn [V][B][D]
  float* pos_part = (float*)d_ws;
  float* neg_part = pos_part + B_N;
  unsigned short* znb = (unsigned short*)((char*)d_ws + 32768);

  norm_pos_kernel<<<B_N, 256, 0, stream>>>(z, znb, pos_part);
  dim3 grid(NTILE, V_N, 1);
  gram_kernel<<<grid, 256, 0, stream>>>(znb, neg_part);
  finalize_kernel<<<1, 1024, 0, stream>>>(pos_part, neg_part, out);
}